// Round 8
// baseline (51.081 us; speedup 1.0000x reference)
//
#include <hip/hip_runtime.h>

#define NB 2048
#define NC 16
#define ND 256
#define OUTW 353
#define THRED 0.8f

typedef short bf16x8 __attribute__((ext_vector_type(8)));
typedef float f32x4 __attribute__((ext_vector_type(4)));
typedef float f32x4a __attribute__((ext_vector_type(4), aligned(4)));

__device__ __forceinline__ short f2s(float x) {      // native cast -> v_cvt_pk_bf16_f32
    __bf16 h = (__bf16)x;
    return __builtin_bit_cast(short, h);
}

__device__ __forceinline__ bf16x8 cvt8(const float4& a, const float4& b) {
    bf16x8 r;
    r[0] = f2s(a.x); r[1] = f2s(a.y); r[2] = f2s(a.z); r[3] = f2s(a.w);
    r[4] = f2s(b.x); r[5] = f2s(b.y); r[6] = f2s(b.z); r[7] = f2s(b.w);
    return r;
}

// One block (256 thr = 4 waves) per b. Wave q owns K-quarter [64q, 64q+64).
// R8 change vs R7: ALL 7 quarter-tiles (own + 6 neighbors) are loaded in one
// burst into distinct registers, fenced with sched_barrier(0), so the wave
// takes ONE memory-latency exposure instead of seven serial ones (R7: VGPR=80
// showed the compiler register-minimized and serialized the loads; ~13K cy
// stalled per wave explained the 45us floor).
__global__ __launch_bounds__(256, 3) void fused_kernel(const float* __restrict__ e,
                                                       const int* __restrict__ nm,
                                                       float* __restrict__ out) {
    __shared__ float red[4][64][33];   // [wave][lane][24 acc + 7 ssq], odd stride -> conflict-free

    const int bid = blockIdx.x;
    const int b   = (bid & 7) * 256 + (bid >> 3);    // XCD-chunked, bijective
    const int q   = threadIdx.x >> 6;                // K-quarter
    const int l   = threadIdx.x & 63;
    const int col = l & 15, hi = l >> 4;
    const int koff = q * 64 + hi * 8;                // chunk0; chunk1 at +32

    // ---- clamped neighbor indices + effective cumulative masks (per lane col) ----
    const int bm1 = (b >= 1) ? b - 1 : 0;
    const int bm2 = (b >= 2) ? b - 2 : 0;
    const int bm3 = (b >= 3) ? b - 3 : 0;
    const int bp1 = (b + 1 < NB) ? b + 1 : NB - 1;
    const int bp2 = (b + 2 < NB) ? b + 2 : NB - 1;
    const int bp3 = (b + 3 < NB) ? b + 3 : NB - 1;

    const float a1 = (b >= 1) ? (float)nm[bm1 * NC + col] : 0.f;
    const float a2 = (b >= 2) ? (float)nm[bm2 * NC + col] : 0.f;
    const float a3 = (b >= 3) ? (float)nm[bm3 * NC + col] : 0.f;
    const float r0 = (float)nm[b * NC + col];
    const float r1 = (b + 1 < NB) ? (float)nm[bp1 * NC + col] : 0.f;
    const float r2 = (b + 2 < NB) ? (float)nm[bp2 * NC + col] : 0.f;

    float em[6];
    em[0] = a1;
    em[1] = a1 * a2;
    em[2] = a1 * a2 * a3;
    em[3] = (b + 1 < NB) ? r0 : 0.f;
    em[4] = (b + 2 < NB) ? r0 * r1 : 0.f;
    em[5] = (b + 3 < NB) ? r0 * r1 * r2 : 0.f;

    const int gbs[6] = {bm1, bm2, bm3, bp1, bp2, bp3};

    // ================= load burst: 7 quarter-tiles, 28 independent loads =================
    const float* rp0 = e + ((size_t)b * NC + col) * ND + koff;
    float4 s0 = *reinterpret_cast<const float4*>(rp0);
    float4 s1 = *reinterpret_cast<const float4*>(rp0 + 4);
    float4 s2 = *reinterpret_cast<const float4*>(rp0 + 32);
    float4 s3 = *reinterpret_cast<const float4*>(rp0 + 36);

    float4 t0[6], t1[6], t2[6], t3[6];
#pragma unroll
    for (int p = 0; p < 6; ++p) {
        const float* rp = e + ((size_t)gbs[p] * NC + col) * ND + koff;
        t0[p] = *reinterpret_cast<const float4*>(rp);
        t1[p] = *reinterpret_cast<const float4*>(rp + 4);
        t2[p] = *reinterpret_cast<const float4*>(rp + 32);
        t3[p] = *reinterpret_cast<const float4*>(rp + 36);
    }
    __builtin_amdgcn_sched_barrier(0);   // all loads issued before any compute

    // ---- own tile: A-frags + ssq partial ----
    bf16x8 af0 = cvt8(s0, s1);
    bf16x8 af1 = cvt8(s2, s3);
    float ssq_own;
    {
        float sq = 0.f;
        sq = fmaf(s0.x, s0.x, sq); sq = fmaf(s0.y, s0.y, sq);
        sq = fmaf(s0.z, s0.z, sq); sq = fmaf(s0.w, s0.w, sq);
        sq = fmaf(s1.x, s1.x, sq); sq = fmaf(s1.y, s1.y, sq);
        sq = fmaf(s1.z, s1.z, sq); sq = fmaf(s1.w, s1.w, sq);
        sq = fmaf(s2.x, s2.x, sq); sq = fmaf(s2.y, s2.y, sq);
        sq = fmaf(s2.z, s2.z, sq); sq = fmaf(s2.w, s2.w, sq);
        sq = fmaf(s3.x, s3.x, sq); sq = fmaf(s3.y, s3.y, sq);
        sq = fmaf(s3.z, s3.z, sq); sq = fmaf(s3.w, s3.w, sq);
        ssq_own = sq;
    }

    // ---- 6 neighbor quarter-tiles: MFMA + ssq + masked neigh accum ----
    float nacc[16];
#pragma unroll
    for (int k = 0; k < 16; ++k) nacc[k] = 0.f;

    float* myred = &red[q][l][0];

#pragma unroll
    for (int p = 0; p < 6; ++p) {
        bf16x8 bf0 = cvt8(t0[p], t1[p]);
        bf16x8 bf1 = cvt8(t2[p], t3[p]);
        f32x4 ac = (f32x4){0.f, 0.f, 0.f, 0.f};
        ac = __builtin_amdgcn_mfma_f32_16x16x32_bf16(af0, bf0, ac, 0, 0, 0);
        ac = __builtin_amdgcn_mfma_f32_16x16x32_bf16(af1, bf1, ac, 0, 0, 0);
        myred[p * 4 + 0] = ac[0];
        myred[p * 4 + 1] = ac[1];
        myred[p * 4 + 2] = ac[2];
        myred[p * 4 + 3] = ac[3];

        float sq = 0.f;
        sq = fmaf(t0[p].x, t0[p].x, sq); sq = fmaf(t0[p].y, t0[p].y, sq);
        sq = fmaf(t0[p].z, t0[p].z, sq); sq = fmaf(t0[p].w, t0[p].w, sq);
        sq = fmaf(t1[p].x, t1[p].x, sq); sq = fmaf(t1[p].y, t1[p].y, sq);
        sq = fmaf(t1[p].z, t1[p].z, sq); sq = fmaf(t1[p].w, t1[p].w, sq);
        sq = fmaf(t2[p].x, t2[p].x, sq); sq = fmaf(t2[p].y, t2[p].y, sq);
        sq = fmaf(t2[p].z, t2[p].z, sq); sq = fmaf(t2[p].w, t2[p].w, sq);
        sq = fmaf(t3[p].x, t3[p].x, sq); sq = fmaf(t3[p].y, t3[p].y, sq);
        sq = fmaf(t3[p].z, t3[p].z, sq); sq = fmaf(t3[p].w, t3[p].w, sq);
        myred[24 + 1 + p] = sq;

        const float m = em[p];
        nacc[0]  = fmaf(m, t0[p].x, nacc[0]);  nacc[1]  = fmaf(m, t0[p].y, nacc[1]);
        nacc[2]  = fmaf(m, t0[p].z, nacc[2]);  nacc[3]  = fmaf(m, t0[p].w, nacc[3]);
        nacc[4]  = fmaf(m, t1[p].x, nacc[4]);  nacc[5]  = fmaf(m, t1[p].y, nacc[5]);
        nacc[6]  = fmaf(m, t1[p].z, nacc[6]);  nacc[7]  = fmaf(m, t1[p].w, nacc[7]);
        nacc[8]  = fmaf(m, t2[p].x, nacc[8]);  nacc[9]  = fmaf(m, t2[p].y, nacc[9]);
        nacc[10] = fmaf(m, t2[p].z, nacc[10]); nacc[11] = fmaf(m, t2[p].w, nacc[11]);
        nacc[12] = fmaf(m, t3[p].x, nacc[12]); nacc[13] = fmaf(m, t3[p].y, nacc[13]);
        nacc[14] = fmaf(m, t3[p].z, nacc[14]); nacc[15] = fmaf(m, t3[p].w, nacc[15]);
    }
    myred[24] = ssq_own;

    // ---- neigh store: lane owns row `col`, dims koff..+7 and koff+32..+39 ----
    {
        const float s6 = 1.0f / 6.0f;
        float* nrow = out + (size_t)(b * NC + col) * OUTW + koff;
        f32x4 v;
        v[0] = nacc[0] * s6;  v[1] = nacc[1] * s6;  v[2] = nacc[2] * s6;  v[3] = nacc[3] * s6;
        *reinterpret_cast<f32x4a*>(nrow) = v;
        v[0] = nacc[4] * s6;  v[1] = nacc[5] * s6;  v[2] = nacc[6] * s6;  v[3] = nacc[7] * s6;
        *reinterpret_cast<f32x4a*>(nrow + 4) = v;
        v[0] = nacc[8] * s6;  v[1] = nacc[9] * s6;  v[2] = nacc[10] * s6; v[3] = nacc[11] * s6;
        *reinterpret_cast<f32x4a*>(nrow + 32) = v;
        v[0] = nacc[12] * s6; v[1] = nacc[13] * s6; v[2] = nacc[14] * s6; v[3] = nacc[15] * s6;
        *reinterpret_cast<f32x4a*>(nrow + 36) = v;
    }

    __syncthreads();
    if (q != 0) return;

    // ================= wave-0 epilogue (slim, two-pass) =================
    float norms[7];
#pragma unroll
    for (int tt = 0; tt < 7; ++tt) {
        float v = red[0][l][24 + tt] + red[1][l][24 + tt]
                + red[2][l][24 + tt] + red[3][l][24 + tt];
        v += __shfl_xor(v, 16, 64);
        v += __shfl_xor(v, 32, 64);
        norms[tt] = sqrtf(v);
    }
    float na[4];
#pragma unroll
    for (int r = 0; r < 4; ++r) na[r] = __shfl(norms[0], hi * 4 + r, 16);

    float acc[24];
#pragma unroll
    for (int k = 0; k < 24; ++k)
        acc[k] = red[0][l][k] + red[1][l][k] + red[2][l][k] + red[3][l][k];

    float rowsum[4] = {0.f, 0.f, 0.f, 0.f};
#pragma unroll
    for (int p = 0; p < 6; ++p) {
        const bool mv = (em[p] != 0.f);
        const float nbv = norms[1 + p];
#pragma unroll
        for (int r = 0; r < 4; ++r) {
            float qd = acc[p * 4 + r] / fmaxf(na[r] * nbv, 1e-8f);
            rowsum[r] += (mv && qd > THRED) ? fminf(qd, 1.f) : 0.f;
        }
    }
#pragma unroll
    for (int r = 0; r < 4; ++r) {
#pragma unroll
        for (int o = 1; o < 16; o <<= 1) rowsum[r] += __shfl_xor(rowsum[r], o, 16);
        rowsum[r] = 1.0f / fmaxf(rowsum[r] + 1.0f, 1e-12f);   // -> inv
    }

#pragma unroll
    for (int r = 0; r < 4; ++r) {
        float* orow = out + (size_t)(b * NC + hi * 4 + r) * OUTW;
#pragma unroll
        for (int p = 0; p < 6; ++p) {
            const bool mv = (em[p] != 0.f);
            float qd = acc[p * 4 + r] / fmaxf(na[r] * norms[1 + p], 1e-8f);
            float sv = (mv && qd > THRED) ? fminf(qd, 1.f) : 0.f;
            orow[ND + p * NC + col] = sv * rowsum[r];
        }
        if (col == 0) orow[ND + 96] = rowsum[r];
    }
}

extern "C" void kernel_launch(void* const* d_in, const int* in_sizes, int n_in,
                              void* d_out, int out_size, void* d_ws, size_t ws_size,
                              hipStream_t stream) {
    const float* e = (const float*)d_in[0];
    const int* nmv = (const int*)d_in[1];
    float* out     = (float*)d_out;
    fused_kernel<<<NB, 256, 0, stream>>>(e, nmv, out);
}